// Round 1
// baseline (558.457 us; speedup 1.0000x reference)
//
#include <hip/hip_runtime.h>
#include <math.h>

#define VV 50257
#define Dm 128
#define NN 256
#define RESN 4096
#define SEQ 512
#define TOK 1024  // B*S

using f32x4_t = __attribute__((ext_vector_type(4))) float;
using s16x8_t = __attribute__((ext_vector_type(8))) short;
using u16x4_t = __attribute__((ext_vector_type(4))) unsigned short;

static __device__ __forceinline__ unsigned short f2bf(float f) {
    unsigned u = __builtin_bit_cast(unsigned, f);
    u += 0x7fffu + ((u >> 16) & 1u);
    return (unsigned short)(u >> 16);
}

// ---------------- pack: invwl/Bp/ac/as float4 tables, transposed cw/opr/opi, LUT ----------------
__global__ void pack_kernel(const float* __restrict__ W, const float* __restrict__ Bp,
                            const float* __restrict__ ac, const float* __restrict__ as_,
                            const float* __restrict__ cw, const float* __restrict__ opr,
                            const float* __restrict__ opi,
                            float4* __restrict__ packed, float* __restrict__ cwT,
                            float* __restrict__ oprT, float* __restrict__ opiT,
                            float2* __restrict__ lutg) {
    int tid = blockIdx.x * 256 + threadIdx.x;  // 0..65535
    int l = tid >> 15;
    int rem = tid & 32767;
    {   // packed[l][d][n]
        int d = rem >> 8, n = rem & 255;
        int src = (l * NN + n) * Dm + d;
        float4 pk;
        pk.x = 1.0f / (1.0f + fabsf(W[src]));
        pk.y = Bp[src];
        pk.z = ac[src];
        pk.w = as_[src];
        packed[tid] = pk;
    }
    {   // cwT[l][k][d] = cw[l][d][k]
        int k = rem >> 7, d = rem & 127;
        cwT[tid] = cw[(l * Dm + d) * (2 * Dm) + k];
    }
    {   // oprT[l][n][d] = opr[l][d][n]
        int n = rem >> 7, d = rem & 127;
        oprT[tid] = opr[(l * Dm + d) * NN + n];
        opiT[tid] = opi[(l * Dm + d) * NN + n];
    }
    if (tid < RESN) {
        float ang = (float)tid * (float)(6.283185307179586476925286766559 / 4096.0);
        lutg[tid] = make_float2(sinf(ang), cosf(ang));
    }
}

// ---------------- embedding gather: x[t][0:256] = emb[ids[t]] ----------------
__global__ void embed_kernel(const int* __restrict__ ids, const float* __restrict__ emb,
                             float* __restrict__ x) {
    int t = blockIdx.x;
    int k = threadIdx.x;
    x[t * 256 + k] = emb[(size_t)ids[t] * 256 + k];
}

// ---------------- xc = x @ cw[l].T + cb[l] : (1024 x 128), K=256 ----------------
__global__ void xc_kernel(const float* __restrict__ x, const float* __restrict__ cwT,
                          const float* __restrict__ cb, float* __restrict__ xc, int l) {
    __shared__ float xs[2][256];
    int tid = threadIdx.x;
    int t0 = blockIdx.x * 2;
    xs[0][tid] = x[t0 * 256 + tid];
    xs[1][tid] = x[(t0 + 1) * 256 + tid];
    __syncthreads();
    int j = tid >> 7, d = tid & 127;
    const float* cwb = cwT + l * 32768;
    float acc = 0.f;
#pragma unroll 8
    for (int k = 0; k < 256; k++) acc = fmaf(xs[j][k], cwb[k * 128 + d], acc);
    xc[(t0 + j) * 128 + d] = acc + cb[l * 128 + d];
}

// ---------------- theta/LUT/reduce over d: partial cos_sum/sin_sum ----------------
// grid (256 token-groups of 4, 2 d-halves); thread = n
__global__ void __launch_bounds__(256) theta_kernel(const float* __restrict__ xc,
                                                    const float4* __restrict__ packed,
                                                    const float2* __restrict__ lutg,
                                                    float* __restrict__ pr_part,
                                                    float* __restrict__ pi_part, int l) {
    __shared__ float2 lut[RESN];
    __shared__ float xcs[4][64];
    int tid = threadIdx.x;
    int t0 = blockIdx.x * 4;
    int dh = blockIdx.y;
    // copy LUT global->LDS (float4 = 2 entries)
    const float4* lg = (const float4*)lutg;
    float4* ldst = (float4*)lut;
#pragma unroll
    for (int i = 0; i < 8; i++) ldst[tid + i * 256] = lg[tid + i * 256];
    {
        int j = tid >> 6, i = tid & 63;
        xcs[j][i] = xc[(t0 + j) * 128 + dh * 64 + i];
    }
    __syncthreads();
    float tv[4];
#pragma unroll
    for (int j = 0; j < 4; j++) {
        int s = (t0 + j) & (SEQ - 1);
        tv[j] = (float)s * 1.61803398874989485f;  // PHI
    }
    const float4* pk = packed + ((size_t)(l * Dm + dh * 64)) * NN + tid;
    float cs[4] = {0, 0, 0, 0}, sn[4] = {0, 0, 0, 0};
    const float SC = (float)(4096.0 / 6.283185307179586476925286766559);
    for (int d = 0; d < 64; d++) {
        float4 p = pk[(size_t)d * NN];
#pragma unroll
        for (int j = 0; j < 4; j++) {
            float th = fmaf(xcs[j][d], p.x, p.y) + tv[j];
            int idx = ((int)floorf(th * SC)) & (RESN - 1);
            float2 scv = lut[idx];
            cs[j] = fmaf(scv.y, p.z, cs[j]);  // cos * attn_cos
            sn[j] = fmaf(scv.x, p.w, sn[j]);  // sin * attn_sin
        }
    }
#pragma unroll
    for (int j = 0; j < 4; j++) {
        pr_part[(size_t)(dh * TOK + t0 + j) * NN + tid] = cs[j];
        pi_part[(size_t)(dh * TOK + t0 + j) * NN + tid] = sn[j];
    }
}

// ---------------- out-proj: x_new = silu(sum @ op.T), writes [xr|xi] layout ----------------
__global__ void proj_kernel(const float* __restrict__ pr_part, const float* __restrict__ pi_part,
                            const float* __restrict__ oprT, const float* __restrict__ opiT,
                            float* __restrict__ x, int l) {
    __shared__ float prs[4][256], pis[4][256];
    int tid = threadIdx.x;
    int t0 = blockIdx.x * 4;
#pragma unroll
    for (int i = 0; i < 4; i++) {
        prs[i][tid] = pr_part[(size_t)(t0 + i) * 256 + tid] +
                      pr_part[(size_t)(TOK + t0 + i) * 256 + tid];
        pis[i][tid] = pi_part[(size_t)(t0 + i) * 256 + tid] +
                      pi_part[(size_t)(TOK + t0 + i) * 256 + tid];
    }
    __syncthreads();
    int g = tid >> 7, d = tid & 127;
    const float* wb = (g == 0 ? oprT : opiT) + l * 32768;
    const float(*ps)[256] = (g == 0) ? prs : pis;
    float acc[4] = {0, 0, 0, 0};
    for (int n = 0; n < 256; n++) {
        float wv = wb[n * 128 + d];
#pragma unroll
        for (int j = 0; j < 4; j++) acc[j] = fmaf(ps[j][n], wv, acc[j]);
    }
#pragma unroll
    for (int j = 0; j < 4; j++) {
        float v = acc[j];
        float s = v / (1.0f + expf(-v));  // silu
        x[(t0 + j) * 256 + g * 128 + d] = s;
    }
}

// ---------------- final complex GEMM + magnitude ----------------
// A = x (1024 x 256 = [xr|xi]); B1 = [Wr|-Wi], B2 = [Wi|Wr] built inline (fp32->bf16)
// out[t][v] = sqrt(lr^2 + li^2 + 1e-8)
__global__ void __launch_bounds__(256, 2) final_kernel(const float* __restrict__ x,
                                                       const float* __restrict__ Wr,
                                                       const float* __restrict__ Wi,
                                                       float* __restrict__ out) {
    __shared__ unsigned short As[128 * 72];
    __shared__ unsigned short B1s[128 * 72];
    __shared__ unsigned short B2s[128 * 72];
    int tid = threadIdx.x;
    int v0 = blockIdx.x * 128;
    int t0 = blockIdx.y * 128;
    int wave = tid >> 6, lane = tid & 63;
    int wm = wave >> 1, wn = wave & 1;
    int quad = lane >> 4, t16 = lane & 15;

    f32x4_t accR[4][4], accI[4][4];
#pragma unroll
    for (int im = 0; im < 4; im++)
#pragma unroll
        for (int in = 0; in < 4; in++) {
            accR[im][in] = (f32x4_t){0.f, 0.f, 0.f, 0.f};
            accI[im][in] = (f32x4_t){0.f, 0.f, 0.f, 0.f};
        }

    for (int kc = 0; kc < 4; kc++) {
        __syncthreads();  // previous compute finished before overwriting LDS
        // --- stage A chunk: x[t0..t0+128][kc*64 .. +64] -> bf16, row stride 72 ---
#pragma unroll
        for (int i = 0; i < 8; i++) {
            int idx = tid + i * 256;
            int row = idx >> 4, c4 = idx & 15;
            float4 a4 = *(const float4*)(x + (size_t)(t0 + row) * 256 + kc * 64 + c4 * 4);
            u16x4_t pkt = {f2bf(a4.x), f2bf(a4.y), f2bf(a4.z), f2bf(a4.w)};
            *(u16x4_t*)(As + row * 72 + c4 * 4) = pkt;
        }
        // --- stage B chunks with complex arrangement ---
        int kbase = (kc & 1) * 64;
#pragma unroll
        for (int i = 0; i < 8; i++) {
            int idx = tid + i * 256;
            int row = idx >> 4, c4 = idx & 15;
            int v = v0 + row;
            if (v >= VV) v = VV - 1;
            float4 r4 = *(const float4*)(Wr + (size_t)v * 128 + kbase + c4 * 4);
            float4 i4 = *(const float4*)(Wi + (size_t)v * 128 + kbase + c4 * 4);
            u16x4_t b1, b2;
            if (kc < 2) {  // k < 128: B1 = Wr, B2 = Wi
                b1 = (u16x4_t){f2bf(r4.x), f2bf(r4.y), f2bf(r4.z), f2bf(r4.w)};
                b2 = (u16x4_t){f2bf(i4.x), f2bf(i4.y), f2bf(i4.z), f2bf(i4.w)};
            } else {       // k >= 128: B1 = -Wi, B2 = Wr
                b1 = (u16x4_t){f2bf(-i4.x), f2bf(-i4.y), f2bf(-i4.z), f2bf(-i4.w)};
                b2 = (u16x4_t){f2bf(r4.x), f2bf(r4.y), f2bf(r4.z), f2bf(r4.w)};
            }
            *(u16x4_t*)(B1s + row * 72 + c4 * 4) = b1;
            *(u16x4_t*)(B2s + row * 72 + c4 * 4) = b2;
        }
        __syncthreads();
        // --- compute: 2 k-steps of 32 ---
#pragma unroll
        for (int ks = 0; ks < 2; ks++) {
            int kofs = ks * 32 + quad * 8;
            s16x8_t af[4], bR[4], bI[4];
#pragma unroll
            for (int im = 0; im < 4; im++)
                af[im] = *(const s16x8_t*)(As + (wm * 64 + im * 16 + t16) * 72 + kofs);
#pragma unroll
            for (int in = 0; in < 4; in++) {
                bR[in] = *(const s16x8_t*)(B1s + (wn * 64 + in * 16 + t16) * 72 + kofs);
                bI[in] = *(const s16x8_t*)(B2s + (wn * 64 + in * 16 + t16) * 72 + kofs);
            }
#pragma unroll
            for (int im = 0; im < 4; im++)
#pragma unroll
                for (int in = 0; in < 4; in++) {
                    accR[im][in] = __builtin_amdgcn_mfma_f32_16x16x32_bf16(
                        af[im], bR[in], accR[im][in], 0, 0, 0);
                    accI[im][in] = __builtin_amdgcn_mfma_f32_16x16x32_bf16(
                        af[im], bI[in], accI[im][in], 0, 0, 0);
                }
        }
    }
    // --- epilogue: magnitude + store (C/D: col=lane&15 -> v, row=quad*4+reg -> t) ---
#pragma unroll
    for (int im = 0; im < 4; im++) {
        int tbase = t0 + wm * 64 + im * 16 + quad * 4;
#pragma unroll
        for (int in = 0; in < 4; in++) {
            int v = v0 + wn * 64 + in * 16 + t16;
            if (v < VV) {
#pragma unroll
                for (int r = 0; r < 4; r++) {
                    float lr = accR[im][in][r];
                    float li = accI[im][in][r];
                    out[(size_t)(tbase + r) * VV + v] = sqrtf(fmaf(lr, lr, fmaf(li, li, 1e-8f)));
                }
            }
        }
    }
}

extern "C" void kernel_launch(void* const* d_in, const int* in_sizes, int n_in,
                              void* d_out, int out_size, void* d_ws, size_t ws_size,
                              hipStream_t stream) {
    const int* ids   = (const int*)d_in[0];
    const float* emb = (const float*)d_in[1];
    const float* cw  = (const float*)d_in[2];
    const float* cb  = (const float*)d_in[3];
    const float* W   = (const float*)d_in[4];
    const float* Bp  = (const float*)d_in[5];
    const float* ac  = (const float*)d_in[6];
    const float* as_ = (const float*)d_in[7];
    const float* opr = (const float*)d_in[8];
    const float* opi = (const float*)d_in[9];
    const float* Wr  = (const float*)d_in[10];
    const float* Wi  = (const float*)d_in[11];
    float* out = (float*)d_out;

    char* ws = (char*)d_ws;
    float*  x       = (float*)(ws);                          // 1 MB (1024x256)
    float*  xc      = (float*)(ws + (1u << 20));             // 512 KB
    float*  pr_part = (float*)(ws + (2u << 20));             // 2 MB (2x1024x256)
    float*  pi_part = (float*)(ws + (4u << 20));             // 2 MB
    float4* packed  = (float4*)(ws + (6u << 20));            // 1 MB (2x128x256 float4)
    float*  cwT     = (float*)(ws + (7u << 20));             // 256 KB
    float*  oprT    = (float*)(ws + (7u << 20) + (256u << 10));
    float*  opiT    = (float*)(ws + (7u << 20) + (512u << 10));
    float2* lutg    = (float2*)(ws + (7u << 20) + (768u << 10));  // 32 KB

    pack_kernel<<<256, 256, 0, stream>>>(W, Bp, ac, as_, cw, opr, opi,
                                         packed, cwT, oprT, opiT, lutg);
    embed_kernel<<<TOK, 256, 0, stream>>>(ids, emb, x);
    for (int l = 0; l < 2; l++) {
        xc_kernel<<<TOK / 2, 256, 0, stream>>>(x, cwT, cb, xc, l);
        theta_kernel<<<dim3(TOK / 4, 2), 256, 0, stream>>>(xc, packed, lutg,
                                                           pr_part, pi_part, l);
        proj_kernel<<<TOK / 4, 256, 0, stream>>>(pr_part, pi_part, oprT, opiT, x, l);
    }
    final_kernel<<<dim3((VV + 127) / 128, TOK / 128), 256, 0, stream>>>(x, Wr, Wi, out);
}